// Round 3
// baseline (8417.764 us; speedup 1.0000x reference)
//
#include <hip/hip_runtime.h>

#define SEQ 384
#define NB  96
#define CH  128
#define ROWS (SEQ*NB)   // 36864

typedef unsigned short ushort;
typedef unsigned int uint;

__device__ __forceinline__ ushort f2b(float f){
  uint u = __float_as_uint(f);
  u += 0x7fffu + ((u >> 16) & 1u);   // RNE
  return (ushort)(u >> 16);
}
__device__ __forceinline__ void unp2(uint u, float& a, float& b){
  a = __uint_as_float(u << 16);
  b = __uint_as_float(u & 0xffff0000u);
}
__device__ __forceinline__ void unp16(const ushort* p, float* f){
  const uint4* q = (const uint4*)p;
  uint4 x = q[0], y = q[1];
  unp2(x.x,f[0],f[1]);  unp2(x.y,f[2],f[3]);  unp2(x.z,f[4],f[5]);  unp2(x.w,f[6],f[7]);
  unp2(y.x,f[8],f[9]);  unp2(y.y,f[10],f[11]); unp2(y.z,f[12],f[13]); unp2(y.w,f[14],f[15]);
}

// ---------------- LayerNorm: fp32 OR bf16 in -> bf16 out, 4 rows/block, wave/row
__global__ __launch_bounds__(256) void ln_kernel(const float* __restrict__ xf,
    const ushort* __restrict__ xb,
    const float* __restrict__ g, const float* __restrict__ b,
    ushort* __restrict__ y)
{
  int row  = blockIdx.x*4 + (threadIdx.x >> 6);
  int lane = threadIdx.x & 63;
  size_t base = (size_t)row*CH + lane*2;
  float2 xv;
  if (xf) xv = *(const float2*)(xf + base);
  else { uint u = *(const uint*)(xb + base); unp2(u, xv.x, xv.y); }
  float s = xv.x + xv.y;
  float q = xv.x*xv.x + xv.y*xv.y;
  #pragma unroll
  for (int off = 32; off >= 1; off >>= 1){
    s += __shfl_xor(s, off);
    q += __shfl_xor(q, off);
  }
  float m  = s * (1.f/CH);
  float var = q * (1.f/CH) - m*m;
  float rs = rsqrtf(var + 1e-5f);
  float2 gv = *(const float2*)(g + lane*2);
  float2 bv = *(const float2*)(b + lane*2);
  ushort2 o;
  o.x = f2b((xv.x - m)*rs*gv.x + bv.x);
  o.y = f2b((xv.y - m)*rs*gv.y + bv.y);
  *(ushort2*)(y + base) = o;
}

// ---------------- GEMM: Y[r, gc] = (X[r,:128] . Wt[gc,:128] + bias[gc])*(gc<sbound?scale:1) (+resid)
// X bf16 [ROWS][128]; tile 128x64; 256 threads; 8x4 per thread.
// Writes fp32 (outf) if non-null, else bf16 (outb).
__global__ __launch_bounds__(256) void gemm_kernel(
  const ushort* __restrict__ Xb,
  const float* __restrict__ Wt, const float* __restrict__ bias,
  int Nn, float scale0, int sbound,
  const float* __restrict__ resid, float* __restrict__ outf, ushort* __restrict__ outb)
{
  __shared__ ushort Xs[128*136];  // [k][row], row-stride 136
  __shared__ ushort Wsh[128*68];  // [k][col], col-stride 68
  int tid = threadIdx.x;
  int R0 = blockIdx.x*128, C0 = blockIdx.y*64;

  #pragma unroll
  for (int i = 0; i < 8; i++){
    int lc = tid + i*256;          // 0..2047
    int row = lc >> 4, kc = (lc & 15)*8;
    uint4 xv = *(const uint4*)(Xb + (size_t)(R0+row)*128 + kc);
    ushort t[8];
    t[0]=(ushort)xv.x; t[1]=(ushort)(xv.x>>16);
    t[2]=(ushort)xv.y; t[3]=(ushort)(xv.y>>16);
    t[4]=(ushort)xv.z; t[5]=(ushort)(xv.z>>16);
    t[6]=(ushort)xv.w; t[7]=(ushort)(xv.w>>16);
    #pragma unroll
    for (int j = 0; j < 8; j++) Xs[(kc+j)*136 + row] = t[j];
  }
  #pragma unroll
  for (int i = 0; i < 8; i++){
    int lc = tid + i*256;          // 0..2047
    int c = lc >> 5, f4 = (lc & 31)*4;
    float4 wv = *(const float4*)(Wt + (size_t)(C0+c)*128 + f4);
    Wsh[(f4+0)*68 + c] = f2b(wv.x);
    Wsh[(f4+1)*68 + c] = f2b(wv.y);
    Wsh[(f4+2)*68 + c] = f2b(wv.z);
    Wsh[(f4+3)*68 + c] = f2b(wv.w);
  }
  __syncthreads();

  int tx = tid & 15, ty = tid >> 4;
  float acc[8][4];
  #pragma unroll
  for (int i = 0; i < 8; i++)
    #pragma unroll
    for (int j = 0; j < 4; j++) acc[i][j] = 0.f;

  #pragma unroll 4
  for (int k = 0; k < 128; k++){
    float a[8], b4[4];
    uint4 av = *(const uint4*)&Xs[k*136 + ty*8];
    unp2(av.x,a[0],a[1]); unp2(av.y,a[2],a[3]); unp2(av.z,a[4],a[5]); unp2(av.w,a[6],a[7]);
    uint2 bv = *(const uint2*)&Wsh[k*68 + tx*4];
    unp2(bv.x,b4[0],b4[1]); unp2(bv.y,b4[2],b4[3]);
    #pragma unroll
    for (int i = 0; i < 8; i++)
      #pragma unroll
      for (int j = 0; j < 4; j++) acc[i][j] = fmaf(a[i], b4[j], acc[i][j]);
  }

  #pragma unroll
  for (int i = 0; i < 8; i++){
    int gr = R0 + ty*8 + i;
    size_t rb = (size_t)gr * Nn;
    #pragma unroll
    for (int j = 0; j < 4; j++){
      int gc = C0 + tx*4 + j;
      float val = acc[i][j] + bias[gc];
      val *= (gc < sbound) ? scale0 : 1.f;
      if (resid) val += resid[(size_t)gr*128 + gc];
      if (outf) outf[rb + gc] = val;
      else      outb[rb + gc] = f2b(val);
    }
  }
}

// ---------------- Relative attention, block = w, thread = (n,h). Online softmax in regs.
// s[v] = q[w,n,h,:].(k[v,n,h,:] + kr[w,v,h,:]) + k[v,n,h,:].qr[w,v,h,:]
// P (qr|kr) computed on the fly from pos/Wi/bi into LDS, 96 v-rows per chunk.
__global__ __launch_bounds__(768) void attn_kernel(
  const ushort* __restrict__ q, int qstride,
  const ushort* __restrict__ kv, int kvstride, int koff, int voff,
  const float* __restrict__ pos, const float* __restrict__ Wi, const float* __restrict__ bi,
  int flip, ushort* __restrict__ vo, float* __restrict__ rawout)
{
  __shared__ ushort Plds[96*256];   // [vc][ch]: ch<128 = qr (scaled), ch>=128 = kr
  const int w = blockIdx.x;
  const int tid = threadIdx.x;      // 0..767
  const int n = tid >> 3, h = tid & 7;

  float qv[16];
  unp16(q + (size_t)((size_t)w*NB + n)*qstride + h*16, qv);

  float S = 0.f, o[16];
  #pragma unroll
  for (int d = 0; d < 16; d++) o[d] = 0.f;

  for (int c = 0; c < 4; c++){
    const int v0 = c*96;
    __syncthreads();
    // stage P chunk: 96 rows x 256 ch; ch maps to Wi row ch (q_r: 0..127, k_r: 128..255)
    for (int oo = tid; oo < 96*256; oo += 768){
      int vc = oo >> 8, ch = oo & 255;
      size_t prow = flip ? ((size_t)(v0+vc)*SEQ + w) : ((size_t)w*SEQ + (v0+vc));
      const float* pp = pos + prow*CH;
      const float* wr = Wi + (size_t)ch*CH;
      float acc = 0.f;
      #pragma unroll 8
      for (int k = 0; k < CH; k += 4){
        float4 a4 = *(const float4*)(pp + k);
        float4 b4 = *(const float4*)(wr + k);
        acc = fmaf(a4.x, b4.x, acc); acc = fmaf(a4.y, b4.y, acc);
        acc = fmaf(a4.z, b4.z, acc); acc = fmaf(a4.w, b4.w, acc);
      }
      acc += bi[ch];
      if (ch < 128) acc *= 0.25f;   // scale = d^-0.5 applied to q_r half only
      Plds[oo] = f2b(acc);
    }
    __syncthreads();

    for (int vc = 0; vc < 96; vc++){
      int v = v0 + vc;
      float qr[16], kr[16], kvv[16], vv[16];
      unp16(&Plds[vc*256 + h*16], qr);
      unp16(&Plds[vc*256 + 128 + h*16], kr);
      const ushort* kvp = kv + (size_t)((size_t)v*NB + n)*kvstride;
      unp16(kvp + koff + h*16, kvv);
      unp16(kvp + voff + h*16, vv);
      float s = 0.f;
      #pragma unroll
      for (int d = 0; d < 16; d++){
        s = fmaf(qv[d], kvv[d] + kr[d], s);
        s = fmaf(kvv[d], qr[d], s);
      }
      if (rawout){
        float r2 = s + __shfl_xor(s, 1);
        r2 += __shfl_xor(r2, 2);
        r2 += __shfl_xor(r2, 4);
        if (h == 0) rawout[(size_t)n*SEQ*SEQ + (size_t)w*SEQ + v] = r2;
      }
      float e = __expf(s);   // |s| <~ 4, no max-sub needed
      S += e;
      #pragma unroll
      for (int d = 0; d < 16; d++) o[d] = fmaf(e, vv[d], o[d]);
    }
  }

  float rS = 1.f / S;
  ushort* op = vo + (size_t)((size_t)w*NB + n)*CH + h*16;
  uint4 p0, p1;
  p0.x = (uint)f2b(o[0]*rS)  | ((uint)f2b(o[1]*rS)<<16);
  p0.y = (uint)f2b(o[2]*rS)  | ((uint)f2b(o[3]*rS)<<16);
  p0.z = (uint)f2b(o[4]*rS)  | ((uint)f2b(o[5]*rS)<<16);
  p0.w = (uint)f2b(o[6]*rS)  | ((uint)f2b(o[7]*rS)<<16);
  p1.x = (uint)f2b(o[8]*rS)  | ((uint)f2b(o[9]*rS)<<16);
  p1.y = (uint)f2b(o[10]*rS) | ((uint)f2b(o[11]*rS)<<16);
  p1.z = (uint)f2b(o[12]*rS) | ((uint)f2b(o[13]*rS)<<16);
  p1.w = (uint)f2b(o[14]*rS) | ((uint)f2b(o[15]*rS)<<16);
  ((uint4*)op)[0] = p0;
  ((uint4*)op)[1] = p1;
}

extern "C" void kernel_launch(void* const* d_in, const int* in_sizes, int n_in,
                              void* d_out, int out_size, void* d_ws, size_t ws_size,
                              hipStream_t stream)
{
  (void)in_sizes; (void)n_in; (void)out_size; (void)ws_size;
  const float* feat_left  = (const float*)d_in[0];
  const float* feat_right = (const float*)d_in[1];
  const float* pos        = (const float*)d_in[2];
  const float* ipw        = (const float*)d_in[3];
  const float* ipb        = (const float*)d_in[4];
  const float* ow         = (const float*)d_in[5];
  const float* ob         = (const float*)d_in[6];
  const float* g1         = (const float*)d_in[7];
  const float* b1         = (const float*)d_in[8];
  const float* g2         = (const float*)d_in[9];
  const float* b2         = (const float*)d_in[10];

  // ws layout (66 MB total):
  //   A: 9.4MB  fl2 -> vob (both MHAs)
  //   B: 9.4MB  fr2 -> fr2n
  //   C: 28.3MB qkvL = full proj(fl2): q(scaled)|k|v  [k/v for MHA1, q for MHA2]
  //   D: 18.9MB qR (MHA1, first half) -> kvR (MHA2)
  char* p = (char*)d_ws;
  ushort* A = (ushort*)p; p += (size_t)ROWS*CH*2;
  ushort* B = (ushort*)p; p += (size_t)ROWS*CH*2;
  ushort* C = (ushort*)p; p += (size_t)ROWS*384*2;
  ushort* D = (ushort*)p; p += (size_t)ROWS*256*2;

  // d_out is FP32 (reference output dtype): feat_left | feat_right | raw_attn
  float* out_fl  = (float*)d_out;
  float* out_fr  = out_fl + (size_t)ROWS*CH;
  float* out_raw = out_fl + (size_t)2*ROWS*CH;

  dim3 b256(256), b768(768);
  dim3 g_ln(ROWS/4);
  dim3 g_qkv(ROWS/128, 384/64);
  dim3 g_q(ROWS/128, 128/64);
  dim3 g_kv(ROWS/128, 256/64);
  dim3 g_attn(SEQ);

  // norm1
  ln_kernel<<<g_ln, b256, 0, stream>>>(feat_left,  nullptr, g1, b1, A);
  ln_kernel<<<g_ln, b256, 0, stream>>>(feat_right, nullptr, g1, b1, B);

  // full qkv proj of left (q scaled by 0.25); q proj of right (scaled)
  gemm_kernel<<<g_qkv, b256, 0, stream>>>(A, ipw, ipb, 384, 0.25f, 128, nullptr, nullptr, C);
  gemm_kernel<<<g_q,   b256, 0, stream>>>(B, ipw, ipb, 128, 0.25f, 128, nullptr, nullptr, D);

  // MHA1: q=right(D), k/v=left(C at ch 128/256), pos flipped
  attn_kernel<<<g_attn, b768, 0, stream>>>(D, 128, C, 384, 128, 256,
                                           pos, ipw, ipb, 1, A, nullptr);
  // out-proj + residual -> feat_right (fp32 to d_out)
  gemm_kernel<<<g_q, b256, 0, stream>>>(A, ow, ob, 128, 1.f, 0, feat_right, out_fr, nullptr);

  // norm2 on updated right features (fp32 input from d_out)
  ln_kernel<<<g_ln, b256, 0, stream>>>(out_fr, nullptr, g2, b2, B);

  // k/v proj of fr2n
  gemm_kernel<<<g_kv, b256, 0, stream>>>(B, ipw + 128*128, ipb + 128, 256, 1.f, 0, nullptr, nullptr, D);

  // MHA2: q=left (q part of C), k/v=D (ch 0/128), pos unflipped, writes raw_attn fp32
  attn_kernel<<<g_attn, b768, 0, stream>>>(C, 384, D, 256, 0, 128,
                                           pos, ipw, ipb, 0, A, out_raw);
  // out-proj + residual -> feat_left (fp32 to d_out)
  gemm_kernel<<<g_q, b256, 0, stream>>>(A, ow, ob, 128, 1.f, 0, feat_left, out_fl, nullptr);
}

// Round 5
// 4132.343 us; speedup vs baseline: 2.0370x; 2.0370x over previous
//
#include <hip/hip_runtime.h>

#define SEQ 384
#define NB  96
#define CH  128
#define ROWS (SEQ*NB)      // 36864
#define PROWS (SEQ*SEQ)    // 147456

typedef unsigned short ushort;
typedef unsigned int uint;

__device__ __forceinline__ ushort f2b(float f){
  uint u = __float_as_uint(f);
  u += 0x7fffu + ((u >> 16) & 1u);   // RNE
  return (ushort)(u >> 16);
}
__device__ __forceinline__ float b2f(ushort s){ return __uint_as_float((uint)s << 16); }
__device__ __forceinline__ void unp2(uint u, float& a, float& b){
  a = __uint_as_float(u << 16);
  b = __uint_as_float(u & 0xffff0000u);
}
__device__ __forceinline__ void unp16u(uint4 a, uint4 b, float* f){
  unp2(a.x,f[0],f[1]);  unp2(a.y,f[2],f[3]);  unp2(a.z,f[4],f[5]);  unp2(a.w,f[6],f[7]);
  unp2(b.x,f[8],f[9]);  unp2(b.y,f[10],f[11]); unp2(b.z,f[12],f[13]); unp2(b.w,f[14],f[15]);
}

// ---------------- LayerNorm: fp32 in -> bf16 out, 4 rows/block, wave/row
__global__ __launch_bounds__(256) void ln_kernel(const float* __restrict__ xf,
    const float* __restrict__ g, const float* __restrict__ b, ushort* __restrict__ y)
{
  int row  = blockIdx.x*4 + (threadIdx.x >> 6);
  int lane = threadIdx.x & 63;
  size_t base = (size_t)row*CH + lane*2;
  float2 xv = *(const float2*)(xf + base);
  float s = xv.x + xv.y;
  float q = xv.x*xv.x + xv.y*xv.y;
  #pragma unroll
  for (int off = 32; off >= 1; off >>= 1){
    s += __shfl_xor(s, off);
    q += __shfl_xor(q, off);
  }
  float m  = s * (1.f/CH);
  float var = q * (1.f/CH) - m*m;
  float rs = rsqrtf(var + 1e-5f);
  float2 gv = *(const float2*)(g + lane*2);
  float2 bv = *(const float2*)(b + lane*2);
  ushort2 o;
  o.x = f2b((xv.x - m)*rs*gv.x + bv.x);
  o.y = f2b((xv.y - m)*rs*gv.y + bv.y);
  *(ushort2*)(y + base) = o;
}

// ---------------- GEMM: out[r, gc] = (X[r,:128] . Wt[gc,:128] + bias[gc])*(gc<sbound?scale:1) (+resid)
// X bf16 (Xb) or fp32 (Xf); tile 128x64; 256 threads; 8x4 per thread; write stride = ostride.
__global__ __launch_bounds__(256) void gemm_kernel(
  const ushort* __restrict__ Xb, const float* __restrict__ Xf,
  const float* __restrict__ Wt, const float* __restrict__ bias,
  int ostride, float scale0, int sbound,
  const float* __restrict__ resid, float* __restrict__ outf, ushort* __restrict__ outb)
{
  __shared__ ushort Xs[128*136];  // [k][row]
  __shared__ ushort Wsh[128*68];  // [k][col]
  int tid = threadIdx.x;
  int R0 = blockIdx.x*128, C0 = blockIdx.y*64;

  #pragma unroll
  for (int i = 0; i < 8; i++){
    int lc = tid + i*256;
    int row = lc >> 4, kc = (lc & 15)*8;
    ushort t[8];
    if (Xb){
      uint4 xv = *(const uint4*)(Xb + (size_t)(R0+row)*128 + kc);
      t[0]=(ushort)xv.x; t[1]=(ushort)(xv.x>>16);
      t[2]=(ushort)xv.y; t[3]=(ushort)(xv.y>>16);
      t[4]=(ushort)xv.z; t[5]=(ushort)(xv.z>>16);
      t[6]=(ushort)xv.w; t[7]=(ushort)(xv.w>>16);
    } else {
      const float4* gp = (const float4*)(Xf + (size_t)(R0+row)*128 + kc);
      float4 a = gp[0], bq = gp[1];
      t[0]=f2b(a.x);  t[1]=f2b(a.y);  t[2]=f2b(a.z);  t[3]=f2b(a.w);
      t[4]=f2b(bq.x); t[5]=f2b(bq.y); t[6]=f2b(bq.z); t[7]=f2b(bq.w);
    }
    #pragma unroll
    for (int j = 0; j < 8; j++) Xs[(kc+j)*136 + row] = t[j];
  }
  #pragma unroll
  for (int i = 0; i < 8; i++){
    int lc = tid + i*256;
    int c = lc >> 5, f4 = (lc & 31)*4;
    float4 wv = *(const float4*)(Wt + (size_t)(C0+c)*128 + f4);
    Wsh[(f4+0)*68 + c] = f2b(wv.x);
    Wsh[(f4+1)*68 + c] = f2b(wv.y);
    Wsh[(f4+2)*68 + c] = f2b(wv.z);
    Wsh[(f4+3)*68 + c] = f2b(wv.w);
  }
  __syncthreads();

  int tx = tid & 15, ty = tid >> 4;
  float acc[8][4];
  #pragma unroll
  for (int i = 0; i < 8; i++)
    #pragma unroll
    for (int j = 0; j < 4; j++) acc[i][j] = 0.f;

  #pragma unroll 4
  for (int k = 0; k < 128; k++){
    float a[8], b4[4];
    uint4 av = *(const uint4*)&Xs[k*136 + ty*8];
    unp2(av.x,a[0],a[1]); unp2(av.y,a[2],a[3]); unp2(av.z,a[4],a[5]); unp2(av.w,a[6],a[7]);
    uint2 bv = *(const uint2*)&Wsh[k*68 + tx*4];
    unp2(bv.x,b4[0],b4[1]); unp2(bv.y,b4[2],b4[3]);
    #pragma unroll
    for (int i = 0; i < 8; i++)
      #pragma unroll
      for (int j = 0; j < 4; j++) acc[i][j] = fmaf(a[i], b4[j], acc[i][j]);
  }

  #pragma unroll
  for (int i = 0; i < 8; i++){
    int gr = R0 + ty*8 + i;
    size_t rb = (size_t)gr * ostride;
    #pragma unroll
    for (int j = 0; j < 4; j++){
      int gc = C0 + tx*4 + j;
      float val = acc[i][j] + bias[gc];
      val *= (gc < sbound) ? scale0 : 1.f;
      if (resid) val += resid[(size_t)gr*128 + gc];
      if (outf) outf[rb + gc] = val;
      else      outb[rb + gc] = f2b(val);
    }
  }
}

// ---------------- Score pass for one h-pair (h = Q*2 + h2, h2 in {0,1}).
// s[n,h,w,v] = q.(k+kr) + k.qr; writes expS[h2][w][v][n] bf16, atomic-adds Ssum[h2][n][w],
// optionally accumulates raw[n][w][v] (sum over the pair) with write(1)/add(2) chaining.
// grid (96, 12); block 256 = 4 waves; wave -> w, lane -> n (two halves 0..63, 64..95).
__global__ __launch_bounds__(256) void score_kernel(
  const ushort* __restrict__ qp, int qstride,
  const ushort* __restrict__ kp, int kstride,
  const ushort* __restrict__ P, int col0, int flip,
  ushort* __restrict__ expS, float* __restrict__ Ssum,
  float* __restrict__ rawp, int rawmode)
{
  __shared__ ushort Ptile[128][64];   // [wl*32+vl][ qr0 16 | qr1 16 | kr0 16 | kr1 16 ]
  __shared__ float rawt[96*129];
  const int tid = threadIdx.x, wave = tid >> 6, lane = tid & 63;
  const int wg = blockIdx.x*4 + wave;
  const int v0 = blockIdx.y*32;

  if (rawmode){
    for (int i = tid; i < 96*129; i += 256) rawt[i] = 0.f;
  }
  // stage P tile: thread t handles row r=t>>1, half part=t&1 (64B = 4 x uint4 each)
  {
    int r = tid >> 1, part = tid & 1;
    int wl = r >> 5, vl = r & 31;
    int wr = blockIdx.x*4 + wl, vv = v0 + vl;
    size_t prow = flip ? ((size_t)vv*SEQ + wr) : ((size_t)wr*SEQ + vv);
    const uint4* src = (const uint4*)(P + prow*256 + (part ? 128 + col0 : col0));
    uint4* dst = (uint4*)(&Ptile[r][part*32]);
    dst[0] = src[0]; dst[1] = src[1]; dst[2] = src[2]; dst[3] = src[3];
  }
  __syncthreads();

  for (int nh = 0; nh < 2; nh++){
    int n = nh*64 + lane;
    bool act = (n < 96);
    float qv[2][16];
    float ss0 = 0.f, ss1 = 0.f;
    if (act){
      const uint4* qs = (const uint4*)(qp + (size_t)((size_t)wg*96 + n)*qstride + col0);
      uint4 a = qs[0], b = qs[1], c = qs[2], d = qs[3];
      unp16u(a, b, qv[0]);
      unp16u(c, d, qv[1]);
    }
    for (int vl = 0; vl < 32; vl++){
      float kv[2][16];
      if (act){
        const uint4* ks = (const uint4*)(kp + (size_t)((size_t)(v0+vl)*96 + n)*kstride + col0);
        uint4 a = ks[0], b = ks[1], c = ks[2], d = ks[3];
        unp16u(a, b, kv[0]);
        unp16u(c, d, kv[1]);
      }
      int r = wave*32 + vl;
      float s0raw = 0.f;
      #pragma unroll
      for (int h2 = 0; h2 < 2; h2++){
        const uint4* pq = (const uint4*)&Ptile[r][h2*16];
        const uint4* pk = (const uint4*)&Ptile[r][32 + h2*16];
        float qr[16], kr[16];
        unp16u(pq[0], pq[1], qr);
        unp16u(pk[0], pk[1], kr);
        float s = 0.f;
        #pragma unroll
        for (int d2 = 0; d2 < 16; d2++)
          s = fmaf(qv[h2][d2], kv[h2][d2] + kr[d2], fmaf(kv[h2][d2], qr[d2], s));
        float e = __expf(s);
        if (act){
          ushort eb = f2b(e);
          float er = b2f(eb);           // use the value PV will see -> consistent softmax
          size_t eidx = ((size_t)(h2*SEQ + wg)*SEQ + (v0+vl))*96 + n;
          expS[eidx] = eb;
          if (h2 == 0){ ss0 += er; s0raw = s; }
          else {
            ss1 += er;
            if (rawmode) rawt[n*129 + wave*32 + vl] += s0raw + s;
          }
        }
      }
    }
    if (act){
      atomicAdd(&Ssum[(size_t)n*SEQ + wg], ss0);
      atomicAdd(&Ssum[(size_t)(96 + n)*SEQ + wg], ss1);
    }
  }

  if (rawmode){
    __syncthreads();
    for (int i = tid; i < 96*128; i += 256){
      int n = i >> 7, c = i & 127;
      float val = rawt[n*129 + c];
      size_t g = ((size_t)n*SEQ + (blockIdx.x*4 + (c >> 5)))*SEQ + v0 + (c & 31);
      if (rawmode == 1) rawp[g] = val;
      else              rawp[g] += val;
    }
  }
}

// ---------------- PV pass for one h-pair: o[w,n,h,:] = sum_v expS * V / Ssum.
// grid (96, 2); block 256 = 4 waves; wave -> w, lane -> n (halves), hl = blockIdx.y.
__global__ __launch_bounds__(256) void pv_kernel(
  const ushort* __restrict__ expS, const float* __restrict__ Ssum,
  const ushort* __restrict__ vp, int vstride,
  ushort* __restrict__ vo, int ocol0)
{
  __shared__ uint Vt[16][8][96];      // [vv][d-pair][n]
  __shared__ ushort Pt[4*16*96];      // [wl][vv][n]
  const int tid = threadIdx.x, wave = tid >> 6, lane = tid & 63;
  const int wg = blockIdx.x*4 + wave;
  const int hl = blockIdx.y;
  const int n1 = 64 + (lane & 31);
  const bool act1 = (lane < 32);

  float o0[16], o1[16];
  #pragma unroll
  for (int d = 0; d < 16; d++){ o0[d] = 0.f; o1[d] = 0.f; }

  for (int vt = 0; vt < 24; vt++){
    __syncthreads();
    for (int i = tid; i < 16*96; i += 256){
      int vv = i/96, n = i - vv*96;
      const uint4* src = (const uint4*)(vp + ((size_t)((size_t)(vt*16+vv)*96 + n))*vstride + hl*16);
      uint4 x = src[0], y = src[1];
      Vt[vv][0][n] = x.x; Vt[vv][1][n] = x.y; Vt[vv][2][n] = x.z; Vt[vv][3][n] = x.w;
      Vt[vv][4][n] = y.x; Vt[vv][5][n] = y.y; Vt[vv][6][n] = y.z; Vt[vv][7][n] = y.w;
    }
    for (int i = tid; i < 3072; i += 256){
      int s2 = i*2;
      int wl = s2/1536; int rem = s2 - wl*1536; int vv = rem/96; int nn = rem - vv*96;
      size_t eidx = ((size_t)(hl*SEQ + blockIdx.x*4 + wl)*SEQ + vt*16 + vv)*96 + nn;
      ((uint*)Pt)[i] = *(const uint*)(expS + eidx);
    }
    __syncthreads();
    #pragma unroll 4
    for (int vv = 0; vv < 16; vv++){
      float p0 = b2f(Pt[(wave*16+vv)*96 + lane]);
      float p1 = act1 ? b2f(Pt[(wave*16+vv)*96 + n1]) : 0.f;
      #pragma unroll
      for (int dp = 0; dp < 8; dp++){
        float a, bb;
        uint u0 = Vt[vv][dp][lane];
        unp2(u0, a, bb);
        o0[2*dp]   = fmaf(p0, a,  o0[2*dp]);
        o0[2*dp+1] = fmaf(p0, bb, o0[2*dp+1]);
        uint u1 = Vt[vv][dp][n1];
        unp2(u1, a, bb);
        o1[2*dp]   = fmaf(p1, a,  o1[2*dp]);
        o1[2*dp+1] = fmaf(p1, bb, o1[2*dp+1]);
      }
    }
  }

  {
    float rs = 1.f / Ssum[(size_t)(hl*96 + lane)*SEQ + wg];
    ushort* op = vo + (size_t)((size_t)wg*96 + lane)*CH + ocol0 + hl*16;
    uint4 w0, w1;
    w0.x = (uint)f2b(o0[0]*rs)  | ((uint)f2b(o0[1]*rs)  << 16);
    w0.y = (uint)f2b(o0[2]*rs)  | ((uint)f2b(o0[3]*rs)  << 16);
    w0.z = (uint)f2b(o0[4]*rs)  | ((uint)f2b(o0[5]*rs)  << 16);
    w0.w = (uint)f2b(o0[6]*rs)  | ((uint)f2b(o0[7]*rs)  << 16);
    w1.x = (uint)f2b(o0[8]*rs)  | ((uint)f2b(o0[9]*rs)  << 16);
    w1.y = (uint)f2b(o0[10]*rs) | ((uint)f2b(o0[11]*rs) << 16);
    w1.z = (uint)f2b(o0[12]*rs) | ((uint)f2b(o0[13]*rs) << 16);
    w1.w = (uint)f2b(o0[14]*rs) | ((uint)f2b(o0[15]*rs) << 16);
    ((uint4*)op)[0] = w0; ((uint4*)op)[1] = w1;
    if (act1){
      float rs1 = 1.f / Ssum[(size_t)(hl*96 + n1)*SEQ + wg];
      ushort* op1 = vo + (size_t)((size_t)wg*96 + n1)*CH + ocol0 + hl*16;
      w0.x = (uint)f2b(o1[0]*rs1)  | ((uint)f2b(o1[1]*rs1)  << 16);
      w0.y = (uint)f2b(o1[2]*rs1)  | ((uint)f2b(o1[3]*rs1)  << 16);
      w0.z = (uint)f2b(o1[4]*rs1)  | ((uint)f2b(o1[5]*rs1)  << 16);
      w0.w = (uint)f2b(o1[6]*rs1)  | ((uint)f2b(o1[7]*rs1)  << 16);
      w1.x = (uint)f2b(o1[8]*rs1)  | ((uint)f2b(o1[9]*rs1)  << 16);
      w1.y = (uint)f2b(o1[10]*rs1) | ((uint)f2b(o1[11]*rs1) << 16);
      w1.z = (uint)f2b(o1[12]*rs1) | ((uint)f2b(o1[13]*rs1) << 16);
      w1.w = (uint)f2b(o1[14]*rs1) | ((uint)f2b(o1[15]*rs1) << 16);
      ((uint4*)op1)[0] = w0; ((uint4*)op1)[1] = w1;
    }
  }
}

extern "C" void kernel_launch(void* const* d_in, const int* in_sizes, int n_in,
                              void* d_out, int out_size, void* d_ws, size_t ws_size,
                              hipStream_t stream)
{
  (void)in_sizes; (void)n_in; (void)out_size; (void)ws_size;
  const float* feat_left  = (const float*)d_in[0];
  const float* feat_right = (const float*)d_in[1];
  const float* pos        = (const float*)d_in[2];
  const float* ipw        = (const float*)d_in[3];
  const float* ipb        = (const float*)d_in[4];
  const float* ow         = (const float*)d_in[5];
  const float* ob         = (const float*)d_in[6];
  const float* g1         = (const float*)d_in[7];
  const float* b1         = (const float*)d_in[8];
  const float* g2         = (const float*)d_in[9];
  const float* b2         = (const float*)d_in[10];

  // ws layout (~179.6 MB):
  char* p = (char*)d_ws;
  ushort* A    = (ushort*)p; p += (size_t)ROWS*CH*2;        //  9.4MB fl2 -> qR -> fr2n
  ushort* B    = (ushort*)p; p += (size_t)ROWS*CH*2;        //  9.4MB fr2 -> attn out (both MHAs)
  ushort* C    = (ushort*)p; p += (size_t)ROWS*384*2;       // 28.3MB q|k|v (left, then right k|v)
  ushort* P    = (ushort*)p; p += (size_t)PROWS*256*2;      // 75.5MB pos-proj: qr(scaled)|kr
  ushort* expS = (ushort*)p; p += (size_t)2*SEQ*SEQ*96*2;   // 56.6MB exp(S) for one h-pair
  float*  Ssum = (float*)p;  p += (size_t)2*96*SEQ*4;       //  0.3MB softmax denominators

  float* out_fl  = (float*)d_out;
  float* out_fr  = out_fl + (size_t)ROWS*CH;
  float* out_raw = out_fl + (size_t)2*ROWS*CH;

  dim3 b256(256);
  dim3 g_ln(ROWS/4);
  dim3 g_score(96, 12), g_pv(96, 2);
  size_t ssum_bytes = (size_t)2*96*SEQ*4;

  // norm1
  ln_kernel<<<g_ln, b256, 0, stream>>>(feat_left,  g1, b1, A);
  ln_kernel<<<g_ln, b256, 0, stream>>>(feat_right, g1, b1, B);

  // fused q|k|v projection of left (q cols scaled); q projection of right -> A (after C done)
  gemm_kernel<<<dim3(288,6), b256, 0, stream>>>(A, nullptr, ipw, ipb, 384, 0.25f, 128, nullptr, nullptr, C);
  gemm_kernel<<<dim3(288,2), b256, 0, stream>>>(B, nullptr, ipw, ipb, 128, 0.25f, 128, nullptr, nullptr, A);

  // P = pos @ Wi[:256].T + bi  (qr half scaled by 0.25), built once for both MHAs
  gemm_kernel<<<dim3(1152,2), b256, 0, stream>>>(nullptr, pos, ipw,          ipb,     256, 0.25f, 128, nullptr, nullptr, P);
  gemm_kernel<<<dim3(1152,2), b256, 0, stream>>>(nullptr, pos, ipw+128*128,  ipb+128, 256, 1.f,   0,   nullptr, nullptr, P+128);

  // MHA1: q = qR (A, stride 128), k/v = left (C+128 / C+256), pos flipped, no raw
  for (int Q = 0; Q < 4; Q++){
    hipMemsetAsync(Ssum, 0, ssum_bytes, stream);
    score_kernel<<<g_score, b256, 0, stream>>>(A, 128, C+128, 384, P, Q*32, 1,
                                               expS, Ssum, nullptr, 0);
    pv_kernel<<<g_pv, b256, 0, stream>>>(expS, Ssum, C+256+Q*32, 384, B, Q*32);
  }
  // out-proj + residual -> feat_right (fp32 to d_out)
  gemm_kernel<<<dim3(288,2), b256, 0, stream>>>(B, nullptr, ow, ob, 128, 1.f, 0, feat_right, out_fr, nullptr);

  // norm2 on updated right -> A
  ln_kernel<<<g_ln, b256, 0, stream>>>(out_fr, g2, b2, A);

  // k/v projection of fr2n into C cols 128..383 (left q preserved in cols 0..127)
  gemm_kernel<<<dim3(288,4), b256, 0, stream>>>(A, nullptr, ipw+128*128, ipb+128, 384, 1.f, 0, nullptr, nullptr, C+128);

  // MHA2: q = left q (C, stride 384), k/v = right (C+128 / C+256), raw chained over quarters
  for (int Q = 0; Q < 4; Q++){
    hipMemsetAsync(Ssum, 0, ssum_bytes, stream);
    score_kernel<<<g_score, b256, 0, stream>>>(C, 384, C+128, 384, P, Q*32, 0,
                                               expS, Ssum, out_raw, (Q == 0) ? 1 : 2);
    pv_kernel<<<g_pv, b256, 0, stream>>>(expS, Ssum, C+256+Q*32, 384, B, Q*32);
  }
  // out-proj + residual -> feat_left (fp32 to d_out)
  gemm_kernel<<<dim3(288,2), b256, 0, stream>>>(B, nullptr, ow, ob, 128, 1.f, 0, feat_left, out_fl, nullptr);
}